// Round 4
// baseline (342.045 us; speedup 1.0000x reference)
//
#include <hip/hip_runtime.h>
#include <hip/hip_bf16.h>
#include <stdint.h>

#define KTAPS 9
#define C_IN 128
#define C_OUT 256
#define HW 56
#define PLANE 3136           // 56*56
#define BATCH 32
#define NPX (BATCH * PLANE)  // 100352
#define KTOT 1152            // 9*128
#define TS 36                // k-steps of 32 (t*4+ks)
#define NGRP (NPX / 16)      // 6272 pixel-groups of 16
#define NBLK64 (NPX / 64)    // 1568 gemm blocks (64 px each)

typedef __attribute__((ext_vector_type(8))) _Float16 f16x8;
typedef __attribute__((ext_vector_type(4))) float f32x4;

static __device__ __forceinline__ uint16_t f2h(float f) {
    _Float16 h = (_Float16)f;
    uint16_t u;
    __builtin_memcpy(&u, &h, 2);
    return u;
}

// ---------------- P1: feature NCHW fp32 -> NHWC f16 ----------------
__global__ void k_feat_nhwc(const float* __restrict__ f, unsigned short* __restrict__ fws) {
    __shared__ float tile[C_IN * 57];
    int blk = blockIdx.x;              // b*56 + y
    int b = blk / HW, y = blk % HW;
    const float* src = f + (size_t)b * C_IN * PLANE + y * HW;
    for (int i = threadIdx.x; i < C_IN * HW; i += 256) {
        int c = i / HW, x = i % HW;
        tile[c * 57 + x] = src[(size_t)c * PLANE + x];
    }
    __syncthreads();
    unsigned short* dst = fws + (size_t)blk * HW * C_IN;
    for (int j = threadIdx.x; j < HW * C_IN; j += 256) {
        int x = j >> 7, c = j & 127;
        dst[j] = f2h(tile[c * 57 + x]);
    }
}

// ---------------- P2: weight -> W3 lane-contiguous fragments ----------------
// W3 idx = (((t*4+ks)*16+mtg)*64+lane)*8+e ; oc = mtg*16+(lane&15), ic = ks*32+(lane>>4)*8+e
__global__ void k_weight(const float* __restrict__ w, unsigned short* __restrict__ W3) {
    int idx = blockIdx.x * 256 + threadIdx.x;
    if (idx >= C_OUT * KTOT) return;
    int e = idx & 7;
    int lane = (idx >> 3) & 63;
    int mtg = (idx >> 9) & 15;
    int ks = (idx >> 13) & 3;
    int t = idx >> 15;                 // 0..8
    int oc = mtg * 16 + (lane & 15);
    int ic = ks * 32 + (lane >> 4) * 8 + e;
    int j = t / 3, i = t % 3;
    W3[idx] = f2h(w[((oc * C_IN + ic) * 3 + j) * 3 + i]);
}

// ---------------- P3: offset [B][18][x][y] -> sxy[tc][px] unnormalized coords ----------------
__global__ void k_coords(const float* __restrict__ off, float* __restrict__ sxy) {
    __shared__ float tile[HW * 57];
    int blk = blockIdx.x;              // b*18 + tc
    int b = blk / 18, tc = blk % 18;
    const float* src = off + (size_t)blk * PLANE;
    for (int i = threadIdx.x; i < PLANE; i += 256) {
        int xx = i / HW, yy = i % HW;
        tile[xx * 57 + yy] = src[i];
    }
    __syncthreads();
    float* dst = sxy + (size_t)tc * NPX + (size_t)b * PLANE;
    bool isx = (tc & 1) == 0;
    for (int p = threadIdx.x; p < PLANE; p += 256) {
        int y = p / HW, x = p % HW;
        float v = tile[x * 57 + y];
        float a = isx ? ((float)x - 27.5f) * (1.0f / 27.5f)
                      : ((float)y - 27.5f) * (1.0f / 27.5f);
        dst[p] = (v + a + 1.0f) * 28.0f - 0.5f;
    }
}

// ---------------- P4a: sampler — gather + bilinear combine -> V4 fragments ----------------
// wave = 16 px (l16) x 4 k-chunks (grp). Per (tap,ks): 4 corner gathers + combine +
// ONE coalesced 1KB store of the MFMA-B fragment V4[lg][ts][lane][8].
// Pure streaming: no LDS, no barriers, 4+ waves/SIMD.
__global__ __launch_bounds__(256, 4) void k_sample(const unsigned short* __restrict__ fws,
                                                   const float* __restrict__ sxy,
                                                   unsigned short* __restrict__ V4,
                                                   int g0) {
    const int tid = threadIdx.x;
    const int wave = tid >> 6, lane = tid & 63;
    const int l16 = lane & 15, grp = lane >> 4;
    const int lg = blockIdx.x * 4 + wave;          // local group (V4 index)
    const int g = g0 + lg;                          // global group
    const int px0 = g * 16;
    const unsigned short* fb = fws + (size_t)(px0 / PLANE) * (PLANE * C_IN) + grp * 8;
    const int p = px0 + l16;
    unsigned short* vout = V4 + (size_t)lg * TS * 512 + lane * 8;

    f16x8 cv[4][4];                   // [corner][ks]
    float swc[4], swn[4];
    const unsigned short *c00, *c10, *c01, *c11;

    auto calc_tap = [&](int t, float* sw) {
        float ixv = sxy[(size_t)(2 * t) * NPX + p];
        float iyv = sxy[(size_t)(2 * t + 1) * NPX + p];
        float fx0 = floorf(ixv), fy0 = floorf(iyv);
        float wx1 = ixv - fx0, wy1 = iyv - fy0;
        float wx0 = 1.0f - wx1, wy0 = 1.0f - wy1;
        int ix0 = (int)fx0, iy0 = (int)fy0;
        int ix1 = ix0 + 1, iy1 = iy0 + 1;
        float vx0 = ((unsigned)ix0 < HW) ? 1.0f : 0.0f;
        float vx1 = ((unsigned)ix1 < HW) ? 1.0f : 0.0f;
        float vy0 = ((unsigned)iy0 < HW) ? 1.0f : 0.0f;
        float vy1 = ((unsigned)iy1 < HW) ? 1.0f : 0.0f;
        int xc0 = min(max(ix0, 0), HW - 1), xc1 = min(max(ix1, 0), HW - 1);
        int yc0 = min(max(iy0, 0), HW - 1), yc1 = min(max(iy1, 0), HW - 1);
        const unsigned short* r0 = fb + (size_t)(yc0 * HW) * C_IN;
        const unsigned short* r1 = fb + (size_t)(yc1 * HW) * C_IN;
        c00 = r0 + xc0 * C_IN; c10 = r0 + xc1 * C_IN;
        c01 = r1 + xc0 * C_IN; c11 = r1 + xc1 * C_IN;
        sw[0] = wx0 * wy0 * vx0 * vy0;
        sw[1] = wx1 * wy0 * vx1 * vy0;
        sw[2] = wx0 * wy1 * vx0 * vy1;
        sw[3] = wx1 * wy1 * vx1 * vy1;
    };

    auto sample_ks = [&](int ks) {
        cv[0][ks] = *(const f16x8*)(c00 + ks * 32);
        cv[1][ks] = *(const f16x8*)(c10 + ks * 32);
        cv[2][ks] = *(const f16x8*)(c01 + ks * 32);
        cv[3][ks] = *(const f16x8*)(c11 + ks * 32);
    };

    calc_tap(0, swc);
#pragma unroll
    for (int ks = 0; ks < 4; ks++) sample_ks(ks);

#pragma unroll
    for (int t = 0; t < KTAPS; t++) {
        const bool more = (t < KTAPS - 1);
        if (more) calc_tap(t + 1, swn);
#pragma unroll
        for (int ks = 0; ks < 4; ks++) {
            f16x8 v = cv[0][ks] * (f16x8)(_Float16)swc[0]
                    + cv[1][ks] * (f16x8)(_Float16)swc[1]
                    + cv[2][ks] * (f16x8)(_Float16)swc[2]
                    + cv[3][ks] * (f16x8)(_Float16)swc[3];
            if (more) sample_ks(ks);             // refill for tap t+1 (new corner ptrs)
            *(f16x8*)(vout + (size_t)(t * 4 + ks) * 512) = v;
        }
        if (more) {
#pragma unroll
            for (int c = 0; c < 4; c++) swc[c] = swn[c];
        }
    }
}

// ---------------- P4b: dense GEMM  out[256][NPX] = W[256][1152] x V ----------------
// block = 64 px (4 groups) x 256 oc, 4 waves; wave = 64 oc x 64 px. acc[4][4] = 64 AGPR.
// Every load is a contiguous 1KB run (A: block-hot W3, B: V4 fragments shared by the
// 4 waves -> L1 hits). Ping-pong prefetch one k-step ahead. No LDS, no barriers.
__global__ __launch_bounds__(256, 3) void k_gemm(const unsigned short* __restrict__ W3,
                                                 const unsigned short* __restrict__ V4,
                                                 float* __restrict__ out,
                                                 int blk0, int nblk) {
    const int tid = threadIdx.x;
    const int wave = tid >> 6, lane = tid & 63;
    const int l16 = lane & 15, grp = lane >> 4;
    const int per = nblk >> 3;                     // nblk % 8 == 0
    const int lb = ((blockIdx.x & 7) * per + (blockIdx.x >> 3));  // XCD-chunked swizzle
    const int px0 = (blk0 + lb) * 64;

    f32x4 acc[4][4];
#pragma unroll
    for (int m = 0; m < 4; m++)
#pragma unroll
        for (int n = 0; n < 4; n++) acc[m][n] = (f32x4)0.0f;

    f16x8 A[2][4], B[2][4];
    const unsigned short* wbase = W3 + (size_t)(wave * 4) * 512 + lane * 8;
    const unsigned short* vbase = V4 + (size_t)(lb * 4) * TS * 512 + lane * 8;

    auto loadAB = [&](int slot, int ts) {
        const unsigned short* wb = wbase + (size_t)ts * 16 * 512;
#pragma unroll
        for (int mt = 0; mt < 4; mt++)
            A[slot][mt] = *(const f16x8*)(wb + mt * 512);
        const unsigned short* vb = vbase + (size_t)ts * 512;
#pragma unroll
        for (int g = 0; g < 4; g++)
            B[slot][g] = *(const f16x8*)(vb + (size_t)g * TS * 512);
    };

    loadAB(0, 0);
#pragma unroll
    for (int ts = 0; ts < TS; ts++) {
        const int cur = ts & 1, nxt = cur ^ 1;
        if (ts < TS - 1) loadAB(nxt, ts + 1);
#pragma unroll
        for (int mt = 0; mt < 4; mt++)
#pragma unroll
            for (int g = 0; g < 4; g++)
                acc[mt][g] = __builtin_amdgcn_mfma_f32_16x16x32_f16(A[cur][mt], B[cur][g], acc[mt][g], 0, 0, 0);
    }

    // epilogue: col px = px0 + g*16 + l16 ; row oc = wave*64 + mt*16 + grp*4 + r
    int bb = px0 / PLANE, rr0 = px0 - bb * PLANE;
    float* obase = out + (size_t)bb * C_OUT * PLANE + rr0 + l16;
#pragma unroll
    for (int g = 0; g < 4; g++) {
        float* ob = obase + g * 16;
#pragma unroll
        for (int mt = 0; mt < 4; mt++) {
#pragma unroll
            for (int r = 0; r < 4; r++) {
                int oc = wave * 64 + mt * 16 + grp * 4 + r;
                ob[(size_t)oc * PLANE] = acc[mt][g][r];
            }
        }
    }
}

// ---------------- fallback: fused sampler+GEMM (R3 structure), ws-light ----------------
__global__ __launch_bounds__(256, 2) void k_fused(const unsigned short* __restrict__ fws,
                                                  const unsigned short* __restrict__ W3,
                                                  const float* __restrict__ sxy,
                                                  float* __restrict__ out) {
    __shared__ float cs[18][64];
    const int tid = threadIdx.x;
    const int wave = tid >> 6, lane = tid & 63;
    const int l16 = lane & 15, grp = lane >> 4;
    const int lbid = (blockIdx.x & 7) * (NBLK64 / 8) + (blockIdx.x >> 3);
    const int px0 = lbid * 64;
    const unsigned short* fb = fws + (size_t)(px0 / PLANE) * (PLANE * C_IN) + grp * 8;
    for (int i = tid; i < 18 * 64; i += 256) {
        int tc = i >> 6, pp = i & 63;
        cs[tc][pp] = sxy[(size_t)tc * NPX + px0 + pp];
    }
    __syncthreads();
    const int p = wave * 16 + l16;
    f32x4 acc[16];
#pragma unroll
    for (int m = 0; m < 16; m++) acc[m] = (f32x4)0.0f;
    f16x8 cv[4][4];
    float swc[4], swn[4];
    const unsigned short *c00, *c10, *c01, *c11;
    auto calc_tap = [&](int t, float* sw) {
        float ixv = cs[2 * t][p], iyv = cs[2 * t + 1][p];
        float fx0 = floorf(ixv), fy0 = floorf(iyv);
        float wx1 = ixv - fx0, wy1 = iyv - fy0;
        float wx0 = 1.0f - wx1, wy0 = 1.0f - wy1;
        int ix0 = (int)fx0, iy0 = (int)fy0, ix1 = ix0 + 1, iy1 = iy0 + 1;
        float vx0 = ((unsigned)ix0 < HW) ? 1.0f : 0.0f;
        float vx1 = ((unsigned)ix1 < HW) ? 1.0f : 0.0f;
        float vy0 = ((unsigned)iy0 < HW) ? 1.0f : 0.0f;
        float vy1 = ((unsigned)iy1 < HW) ? 1.0f : 0.0f;
        int xc0 = min(max(ix0, 0), HW - 1), xc1 = min(max(ix1, 0), HW - 1);
        int yc0 = min(max(iy0, 0), HW - 1), yc1 = min(max(iy1, 0), HW - 1);
        const unsigned short* r0 = fb + (size_t)(yc0 * HW) * C_IN;
        const unsigned short* r1 = fb + (size_t)(yc1 * HW) * C_IN;
        c00 = r0 + xc0 * C_IN; c10 = r0 + xc1 * C_IN;
        c01 = r1 + xc0 * C_IN; c11 = r1 + xc1 * C_IN;
        sw[0] = wx0 * wy0 * vx0 * vy0; sw[1] = wx1 * wy0 * vx1 * vy0;
        sw[2] = wx0 * wy1 * vx0 * vy1; sw[3] = wx1 * wy1 * vx1 * vy1;
    };
    auto sample_ks = [&](int ks) {
        cv[0][ks] = *(const f16x8*)(c00 + ks * 32);
        cv[1][ks] = *(const f16x8*)(c10 + ks * 32);
        cv[2][ks] = *(const f16x8*)(c01 + ks * 32);
        cv[3][ks] = *(const f16x8*)(c11 + ks * 32);
    };
    calc_tap(0, swc);
#pragma unroll
    for (int ks = 0; ks < 4; ks++) sample_ks(ks);
#pragma unroll
    for (int t = 0; t < KTAPS; t++) {
        const bool more = (t < KTAPS - 1);
        if (more) calc_tap(t + 1, swn);
#pragma unroll
        for (int ks = 0; ks < 4; ks++) {
            f16x8 v = cv[0][ks] * (f16x8)(_Float16)swc[0]
                    + cv[1][ks] * (f16x8)(_Float16)swc[1]
                    + cv[2][ks] * (f16x8)(_Float16)swc[2]
                    + cv[3][ks] * (f16x8)(_Float16)swc[3];
            const unsigned short* wb = W3 + (size_t)(t * 4 + ks) * 8192 + lane * 8;
            f16x8 af[16];
#pragma unroll
            for (int mtg = 0; mtg < 16; mtg++)
                af[mtg] = *(const f16x8*)(wb + mtg * 512);
            if (more) sample_ks(ks);
#pragma unroll
            for (int mtg = 0; mtg < 16; mtg++)
                acc[mtg] = __builtin_amdgcn_mfma_f32_16x16x32_f16(af[mtg], v, acc[mtg], 0, 0, 0);
        }
        if (more) {
#pragma unroll
            for (int c = 0; c < 4; c++) swc[c] = swn[c];
        }
    }
    int bb = px0 / PLANE, rr = px0 - bb * PLANE + p;
    float* ob = out + (size_t)bb * C_OUT * PLANE + rr;
#pragma unroll
    for (int mtg = 0; mtg < 16; mtg++)
#pragma unroll
        for (int r = 0; r < 4; r++)
            ob[(size_t)(mtg * 16 + grp * 4 + r) * PLANE] = acc[mtg][r];
}

extern "C" void kernel_launch(void* const* d_in, const int* in_sizes, int n_in,
                              void* d_out, int out_size, void* d_ws, size_t ws_size,
                              hipStream_t stream) {
    const float* feature = (const float*)d_in[0];
    const float* offset = (const float*)d_in[1];
    const float* weight = (const float*)d_in[2];
    float* out = (float*)d_out;

    char* ws = (char*)d_ws;
    unsigned short* fws = (unsigned short*)ws;                          // 25,690,112 B
    unsigned short* W3 = (unsigned short*)(ws + 25690112);              // 589,824 B
    float* sxy = (float*)(ws + 25690112 + 589824);                      // 7,225,344 B
    const size_t base = 25690112 + 589824 + 7225344;                    // 33,505,280 B
    const size_t v4_full = (size_t)NPX * KTOT * 2;                      // 231,211,008 B
    unsigned short* V4 = (unsigned short*)(ws + base);

    k_feat_nhwc<<<BATCH * HW, 256, 0, stream>>>(feature, fws);
    k_weight<<<(C_OUT * KTOT + 255) / 256, 256, 0, stream>>>(weight, W3);
    k_coords<<<BATCH * 18, 256, 0, stream>>>(offset, sxy);

    if (ws_size >= base + v4_full) {
        // full split: one sampler pass, one GEMM pass
        k_sample<<<NGRP / 4, 256, 0, stream>>>(fws, sxy, V4, 0);
        k_gemm<<<NBLK64, 256, 0, stream>>>(W3, V4, out, 0, NBLK64);
    } else if (ws_size >= base + v4_full / 2) {
        // 2-chunk split, single half-buffer (stream-serial keeps it correct)
        k_sample<<<NGRP / 8, 256, 0, stream>>>(fws, sxy, V4, 0);
        k_gemm<<<NBLK64 / 2, 256, 0, stream>>>(W3, V4, out, 0, NBLK64 / 2);
        k_sample<<<NGRP / 8, 256, 0, stream>>>(fws, sxy, V4, NGRP / 2);
        k_gemm<<<NBLK64 / 2, 256, 0, stream>>>(W3, V4, out, NBLK64 / 2, NBLK64 / 2);
    } else {
        k_fused<<<NBLK64, 256, 0, stream>>>(fws, W3, sxy, out);
    }
}

// Round 5
// 308.952 us; speedup vs baseline: 1.1071x; 1.1071x over previous
//
#include <hip/hip_runtime.h>
#include <hip/hip_bf16.h>
#include <stdint.h>

#define KTAPS 9
#define C_IN 128
#define C_OUT 256
#define HW 56
#define PLANE 3136           // 56*56
#define BATCH 32
#define NPX (BATCH * PLANE)  // 100352
#define KTOT 1152            // 9*128
#define TS 36                // k-steps of 32 (t*4+ks)
#define NGRP (NPX / 16)      // 6272 pixel-groups of 16
#define NBLK64 (NPX / 64)    // 1568 gemm blocks (64 px each)

typedef __attribute__((ext_vector_type(8))) _Float16 f16x8;
typedef __attribute__((ext_vector_type(4))) float f32x4;

static __device__ __forceinline__ uint16_t f2h(float f) {
    _Float16 h = (_Float16)f;
    uint16_t u;
    __builtin_memcpy(&u, &h, 2);
    return u;
}

// ---------------- P1: feature NCHW fp32 -> NHWC f16 ----------------
__global__ void k_feat_nhwc(const float* __restrict__ f, unsigned short* __restrict__ fws) {
    __shared__ float tile[C_IN * 57];
    int blk = blockIdx.x;              // b*56 + y
    int b = blk / HW, y = blk % HW;
    const float* src = f + (size_t)b * C_IN * PLANE + y * HW;
    for (int i = threadIdx.x; i < C_IN * HW; i += 256) {
        int c = i / HW, x = i % HW;
        tile[c * 57 + x] = src[(size_t)c * PLANE + x];
    }
    __syncthreads();
    unsigned short* dst = fws + (size_t)blk * HW * C_IN;
    for (int j = threadIdx.x; j < HW * C_IN; j += 256) {
        int x = j >> 7, c = j & 127;
        dst[j] = f2h(tile[c * 57 + x]);
    }
}

// ---------------- P2: weight -> W3 lane-contiguous fragments ----------------
// W3 idx = (((t*4+ks)*16+mtg)*64+lane)*8+e ; oc = mtg*16+(lane&15), ic = ks*32+(lane>>4)*8+e
__global__ void k_weight(const float* __restrict__ w, unsigned short* __restrict__ W3) {
    int idx = blockIdx.x * 256 + threadIdx.x;
    if (idx >= C_OUT * KTOT) return;
    int e = idx & 7;
    int lane = (idx >> 3) & 63;
    int mtg = (idx >> 9) & 15;
    int ks = (idx >> 13) & 3;
    int t = idx >> 15;                 // 0..8
    int oc = mtg * 16 + (lane & 15);
    int ic = ks * 32 + (lane >> 4) * 8 + e;
    int j = t / 3, i = t % 3;
    W3[idx] = f2h(w[((oc * C_IN + ic) * 3 + j) * 3 + i]);
}

// ---------------- P3: offset [B][18][x][y] -> sxy[tc][px] unnormalized coords ----------------
__global__ void k_coords(const float* __restrict__ off, float* __restrict__ sxy) {
    __shared__ float tile[HW * 57];
    int blk = blockIdx.x;              // b*18 + tc
    int b = blk / 18, tc = blk % 18;
    const float* src = off + (size_t)blk * PLANE;
    for (int i = threadIdx.x; i < PLANE; i += 256) {
        int xx = i / HW, yy = i % HW;
        tile[xx * 57 + yy] = src[i];
    }
    __syncthreads();
    float* dst = sxy + (size_t)tc * NPX + (size_t)b * PLANE;
    bool isx = (tc & 1) == 0;
    for (int p = threadIdx.x; p < PLANE; p += 256) {
        int y = p / HW, x = p % HW;
        float v = tile[x * 57 + y];
        float a = isx ? ((float)x - 27.5f) * (1.0f / 27.5f)
                      : ((float)y - 27.5f) * (1.0f / 27.5f);
        dst[p] = (v + a + 1.0f) * 28.0f - 0.5f;
    }
}

// ---------------- P4a: sampler — gather + bilinear combine -> V4 fragments ----------------
// R5 changes: (1) XCD-chunked block swizzle -> each XCD walks a CONTIGUOUS pixel range,
// instantaneous per-XCD gather working set ~2-3MB < 4MB L2 (was: all 32 images
// interleaved -> L2 thrash -> 406MB HBM fetch); (2) 8 waves/EU (32 VGPR, no LDS)
// for max memory-level parallelism.
__global__ __launch_bounds__(256, 8) void k_sample(const unsigned short* __restrict__ fws,
                                                   const float* __restrict__ sxy,
                                                   unsigned short* __restrict__ V4,
                                                   int g0, int nblk) {
    const int tid = threadIdx.x;
    const int wave = tid >> 6, lane = tid & 63;
    const int l16 = lane & 15, grp = lane >> 4;
    const int per = nblk >> 3;                      // nblk % 8 == 0
    const int sbid = (blockIdx.x & 7) * per + (blockIdx.x >> 3);   // XCD-chunked swizzle
    const int lg = sbid * 4 + wave;                 // chunk-local group (V4 index)
    const int g = g0 + lg;                          // global group
    const int px0 = g * 16;
    const unsigned short* fb = fws + (size_t)(px0 / PLANE) * (PLANE * C_IN) + grp * 8;
    const int p = px0 + l16;
    unsigned short* vout = V4 + (size_t)lg * TS * 512 + lane * 8;

    f16x8 cv[4][4];                   // [corner][ks]
    float swc[4], swn[4];
    const unsigned short *c00, *c10, *c01, *c11;

    auto calc_tap = [&](int t, float* sw) {
        float ixv = sxy[(size_t)(2 * t) * NPX + p];
        float iyv = sxy[(size_t)(2 * t + 1) * NPX + p];
        float fx0 = floorf(ixv), fy0 = floorf(iyv);
        float wx1 = ixv - fx0, wy1 = iyv - fy0;
        float wx0 = 1.0f - wx1, wy0 = 1.0f - wy1;
        int ix0 = (int)fx0, iy0 = (int)fy0;
        int ix1 = ix0 + 1, iy1 = iy0 + 1;
        float vx0 = ((unsigned)ix0 < HW) ? 1.0f : 0.0f;
        float vx1 = ((unsigned)ix1 < HW) ? 1.0f : 0.0f;
        float vy0 = ((unsigned)iy0 < HW) ? 1.0f : 0.0f;
        float vy1 = ((unsigned)iy1 < HW) ? 1.0f : 0.0f;
        int xc0 = min(max(ix0, 0), HW - 1), xc1 = min(max(ix1, 0), HW - 1);
        int yc0 = min(max(iy0, 0), HW - 1), yc1 = min(max(iy1, 0), HW - 1);
        const unsigned short* r0 = fb + (size_t)(yc0 * HW) * C_IN;
        const unsigned short* r1 = fb + (size_t)(yc1 * HW) * C_IN;
        c00 = r0 + xc0 * C_IN; c10 = r0 + xc1 * C_IN;
        c01 = r1 + xc0 * C_IN; c11 = r1 + xc1 * C_IN;
        sw[0] = wx0 * wy0 * vx0 * vy0;
        sw[1] = wx1 * wy0 * vx1 * vy0;
        sw[2] = wx0 * wy1 * vx0 * vy1;
        sw[3] = wx1 * wy1 * vx1 * vy1;
    };

    auto sample_ks = [&](int ks) {
        cv[0][ks] = *(const f16x8*)(c00 + ks * 32);
        cv[1][ks] = *(const f16x8*)(c10 + ks * 32);
        cv[2][ks] = *(const f16x8*)(c01 + ks * 32);
        cv[3][ks] = *(const f16x8*)(c11 + ks * 32);
    };

    calc_tap(0, swc);
#pragma unroll
    for (int ks = 0; ks < 4; ks++) sample_ks(ks);

#pragma unroll
    for (int t = 0; t < KTAPS; t++) {
        const bool more = (t < KTAPS - 1);
        if (more) calc_tap(t + 1, swn);
#pragma unroll
        for (int ks = 0; ks < 4; ks++) {
            f16x8 v = cv[0][ks] * (f16x8)(_Float16)swc[0]
                    + cv[1][ks] * (f16x8)(_Float16)swc[1]
                    + cv[2][ks] * (f16x8)(_Float16)swc[2]
                    + cv[3][ks] * (f16x8)(_Float16)swc[3];
            if (more) sample_ks(ks);             // refill for tap t+1 (new corner ptrs)
            *(f16x8*)(vout + (size_t)(t * 4 + ks) * 512) = v;
        }
        if (more) {
#pragma unroll
            for (int c = 0; c < 4; c++) swc[c] = swn[c];
        }
    }
}

// ---------------- P4b: dense GEMM  out[256][NPX] = W[256][1152] x V ----------------
// block = 64 px (4 groups) x 256 oc, 4 waves; wave = 64 oc x 64 px. acc[4][4] = 64 AGPR.
// R5: B (V4, streamed from HBM/L3, ~900cyc latency) uses a 3-slot ring prefetched
// 2 k-steps ahead (~460+cyc of MFMA cover at 3 waves/SIMD); A (L2-hot W3) stays
// ping-pong 1 ahead. Fully unrolled -> all slot indices compile-time (no scratch).
__global__ __launch_bounds__(256, 3) void k_gemm(const unsigned short* __restrict__ W3,
                                                 const unsigned short* __restrict__ V4,
                                                 float* __restrict__ out,
                                                 int blk0, int nblk) {
    const int tid = threadIdx.x;
    const int wave = tid >> 6, lane = tid & 63;
    const int l16 = lane & 15, grp = lane >> 4;
    const int per = nblk >> 3;                     // nblk % 8 == 0
    const int lb = ((blockIdx.x & 7) * per + (blockIdx.x >> 3));  // XCD-chunked swizzle
    const int px0 = (blk0 + lb) * 64;

    f32x4 acc[4][4];
#pragma unroll
    for (int m = 0; m < 4; m++)
#pragma unroll
        for (int n = 0; n < 4; n++) acc[m][n] = (f32x4)0.0f;

    f16x8 A[2][4], B[3][4];
    const unsigned short* wbase = W3 + (size_t)(wave * 4) * 512 + lane * 8;
    const unsigned short* vbase = V4 + (size_t)(lb * 4) * TS * 512 + lane * 8;

    auto loadA = [&](int slot, int ts) {
        const unsigned short* wb = wbase + (size_t)ts * 16 * 512;
#pragma unroll
        for (int mt = 0; mt < 4; mt++)
            A[slot][mt] = *(const f16x8*)(wb + mt * 512);
    };
    auto loadB = [&](int slot, int ts) {
        const unsigned short* vb = vbase + (size_t)ts * 512;
#pragma unroll
        for (int g = 0; g < 4; g++)
            B[slot][g] = *(const f16x8*)(vb + (size_t)g * TS * 512);
    };

    loadB(0, 0);
    loadB(1, 1);
    loadA(0, 0);
#pragma unroll
    for (int ts = 0; ts < TS; ts++) {
        if (ts + 2 < TS) loadB((ts + 2) % 3, ts + 2);
        if (ts + 1 < TS) loadA((ts + 1) & 1, ts + 1);
        const int ca = ts & 1, cb = ts % 3;
#pragma unroll
        for (int mt = 0; mt < 4; mt++)
#pragma unroll
            for (int g = 0; g < 4; g++)
                acc[mt][g] = __builtin_amdgcn_mfma_f32_16x16x32_f16(A[ca][mt], B[cb][g], acc[mt][g], 0, 0, 0);
    }

    // epilogue: col px = px0 + g*16 + l16 ; row oc = wave*64 + mt*16 + grp*4 + r
    int bb = px0 / PLANE, rr0 = px0 - bb * PLANE;
    float* obase = out + (size_t)bb * C_OUT * PLANE + rr0 + l16;
#pragma unroll
    for (int g = 0; g < 4; g++) {
        float* ob = obase + g * 16;
#pragma unroll
        for (int mt = 0; mt < 4; mt++) {
#pragma unroll
            for (int r = 0; r < 4; r++) {
                int oc = wave * 64 + mt * 16 + grp * 4 + r;
                ob[(size_t)oc * PLANE] = acc[mt][g][r];
            }
        }
    }
}

// ---------------- fallback: fused sampler+GEMM (R3 structure), ws-light ----------------
__global__ __launch_bounds__(256, 2) void k_fused(const unsigned short* __restrict__ fws,
                                                  const unsigned short* __restrict__ W3,
                                                  const float* __restrict__ sxy,
                                                  float* __restrict__ out) {
    __shared__ float cs[18][64];
    const int tid = threadIdx.x;
    const int wave = tid >> 6, lane = tid & 63;
    const int l16 = lane & 15, grp = lane >> 4;
    const int lbid = (blockIdx.x & 7) * (NBLK64 / 8) + (blockIdx.x >> 3);
    const int px0 = lbid * 64;
    const unsigned short* fb = fws + (size_t)(px0 / PLANE) * (PLANE * C_IN) + grp * 8;
    for (int i = tid; i < 18 * 64; i += 256) {
        int tc = i >> 6, pp = i & 63;
        cs[tc][pp] = sxy[(size_t)tc * NPX + px0 + pp];
    }
    __syncthreads();
    const int p = wave * 16 + l16;
    f32x4 acc[16];
#pragma unroll
    for (int m = 0; m < 16; m++) acc[m] = (f32x4)0.0f;
    f16x8 cv[4][4];
    float swc[4], swn[4];
    const unsigned short *c00, *c10, *c01, *c11;
    auto calc_tap = [&](int t, float* sw) {
        float ixv = cs[2 * t][p], iyv = cs[2 * t + 1][p];
        float fx0 = floorf(ixv), fy0 = floorf(iyv);
        float wx1 = ixv - fx0, wy1 = iyv - fy0;
        float wx0 = 1.0f - wx1, wy0 = 1.0f - wy1;
        int ix0 = (int)fx0, iy0 = (int)fy0, ix1 = ix0 + 1, iy1 = iy0 + 1;
        float vx0 = ((unsigned)ix0 < HW) ? 1.0f : 0.0f;
        float vx1 = ((unsigned)ix1 < HW) ? 1.0f : 0.0f;
        float vy0 = ((unsigned)iy0 < HW) ? 1.0f : 0.0f;
        float vy1 = ((unsigned)iy1 < HW) ? 1.0f : 0.0f;
        int xc0 = min(max(ix0, 0), HW - 1), xc1 = min(max(ix1, 0), HW - 1);
        int yc0 = min(max(iy0, 0), HW - 1), yc1 = min(max(iy1, 0), HW - 1);
        const unsigned short* r0 = fb + (size_t)(yc0 * HW) * C_IN;
        const unsigned short* r1 = fb + (size_t)(yc1 * HW) * C_IN;
        c00 = r0 + xc0 * C_IN; c10 = r0 + xc1 * C_IN;
        c01 = r1 + xc0 * C_IN; c11 = r1 + xc1 * C_IN;
        sw[0] = wx0 * wy0 * vx0 * vy0; sw[1] = wx1 * wy0 * vx1 * vy0;
        sw[2] = wx0 * wy1 * vx0 * vy1; sw[3] = wx1 * wy1 * vx1 * vy1;
    };
    auto sample_ks = [&](int ks) {
        cv[0][ks] = *(const f16x8*)(c00 + ks * 32);
        cv[1][ks] = *(const f16x8*)(c10 + ks * 32);
        cv[2][ks] = *(const f16x8*)(c01 + ks * 32);
        cv[3][ks] = *(const f16x8*)(c11 + ks * 32);
    };
    calc_tap(0, swc);
#pragma unroll
    for (int ks = 0; ks < 4; ks++) sample_ks(ks);
#pragma unroll
    for (int t = 0; t < KTAPS; t++) {
        const bool more = (t < KTAPS - 1);
        if (more) calc_tap(t + 1, swn);
#pragma unroll
        for (int ks = 0; ks < 4; ks++) {
            f16x8 v = cv[0][ks] * (f16x8)(_Float16)swc[0]
                    + cv[1][ks] * (f16x8)(_Float16)swc[1]
                    + cv[2][ks] * (f16x8)(_Float16)swc[2]
                    + cv[3][ks] * (f16x8)(_Float16)swc[3];
            const unsigned short* wb = W3 + (size_t)(t * 4 + ks) * 8192 + lane * 8;
            f16x8 af[16];
#pragma unroll
            for (int mtg = 0; mtg < 16; mtg++)
                af[mtg] = *(const f16x8*)(wb + mtg * 512);
            if (more) sample_ks(ks);
#pragma unroll
            for (int mtg = 0; mtg < 16; mtg++)
                acc[mtg] = __builtin_amdgcn_mfma_f32_16x16x32_f16(af[mtg], v, acc[mtg], 0, 0, 0);
        }
        if (more) {
#pragma unroll
            for (int c = 0; c < 4; c++) swc[c] = swn[c];
        }
    }
    int bb = px0 / PLANE, rr = px0 - bb * PLANE + p;
    float* ob = out + (size_t)bb * C_OUT * PLANE + rr;
#pragma unroll
    for (int mtg = 0; mtg < 16; mtg++)
#pragma unroll
        for (int r = 0; r < 4; r++)
            ob[(size_t)(mtg * 16 + grp * 4 + r) * PLANE] = acc[mtg][r];
}

extern "C" void kernel_launch(void* const* d_in, const int* in_sizes, int n_in,
                              void* d_out, int out_size, void* d_ws, size_t ws_size,
                              hipStream_t stream) {
    const float* feature = (const float*)d_in[0];
    const float* offset = (const float*)d_in[1];
    const float* weight = (const float*)d_in[2];
    float* out = (float*)d_out;

    char* ws = (char*)d_ws;
    unsigned short* fws = (unsigned short*)ws;                          // 25,690,112 B
    unsigned short* W3 = (unsigned short*)(ws + 25690112);              // 589,824 B
    float* sxy = (float*)(ws + 25690112 + 589824);                      // 7,225,344 B
    const size_t base = 25690112 + 589824 + 7225344;                    // 33,505,280 B
    const size_t v4_full = (size_t)NPX * KTOT * 2;                      // 231,211,008 B
    unsigned short* V4 = (unsigned short*)(ws + base);

    k_feat_nhwc<<<BATCH * HW, 256, 0, stream>>>(feature, fws);
    k_weight<<<(C_OUT * KTOT + 255) / 256, 256, 0, stream>>>(weight, W3);
    k_coords<<<BATCH * 18, 256, 0, stream>>>(offset, sxy);

    if (ws_size >= base + v4_full) {
        // full split: one sampler pass, one GEMM pass
        k_sample<<<NGRP / 4, 256, 0, stream>>>(fws, sxy, V4, 0, NGRP / 4);
        k_gemm<<<NBLK64, 256, 0, stream>>>(W3, V4, out, 0, NBLK64);
    } else if (ws_size >= base + v4_full / 2) {
        // 2-chunk split, single half-buffer (stream-serial keeps it correct)
        k_sample<<<NGRP / 8, 256, 0, stream>>>(fws, sxy, V4, 0, NGRP / 8);
        k_gemm<<<NBLK64 / 2, 256, 0, stream>>>(W3, V4, out, 0, NBLK64 / 2);
        k_sample<<<NGRP / 8, 256, 0, stream>>>(fws, sxy, V4, NGRP / 2, NGRP / 8);
        k_gemm<<<NBLK64 / 2, 256, 0, stream>>>(W3, V4, out, NBLK64 / 2, NBLK64 / 2);
    } else {
        k_fused<<<NBLK64, 256, 0, stream>>>(fws, W3, sxy, out);
    }
}

// Round 7
// 226.718 us; speedup vs baseline: 1.5087x; 1.3627x over previous
//
#include <hip/hip_runtime.h>
#include <hip/hip_bf16.h>
#include <stdint.h>

#define KTAPS 9
#define C_IN 128
#define C_OUT 256
#define HW 56
#define PLANE 3136           // 56*56
#define BATCH 32
#define NPX (BATCH * PLANE)  // 100352
#define KTOT 1152            // 9*128
#define NBLK64 (NPX / 64)    // 1568 blocks (64 px each)
#define BPER (NBLK64 / 8)    // 196
#define VBLK_STRIDE (KTAPS * 16384)   // 147456 B per 64-px block in V4

typedef __attribute__((ext_vector_type(8))) _Float16 f16x8;
typedef __attribute__((ext_vector_type(2))) _Float16 f16x2;
typedef __attribute__((ext_vector_type(4))) float f32x4;
typedef __attribute__((ext_vector_type(4))) unsigned int u32x4;

static __device__ __forceinline__ uint16_t f2h(float f) {
    _Float16 h = (_Float16)f;
    uint16_t u;
    __builtin_memcpy(&u, &h, 2);
    return u;
}

// ---------------- P1: feature NCHW fp32 -> NHWC f16 ----------------
__global__ void k_feat_nhwc(const float* __restrict__ f, unsigned short* __restrict__ fws) {
    __shared__ float tile[C_IN * 57];
    int blk = blockIdx.x;              // b*56 + y
    int b = blk / HW, y = blk % HW;
    const float* src = f + (size_t)b * C_IN * PLANE + y * HW;
    for (int i = threadIdx.x; i < C_IN * HW; i += 256) {
        int c = i / HW, x = i % HW;
        tile[c * 57 + x] = src[(size_t)c * PLANE + x];
    }
    __syncthreads();
    unsigned short* dst = fws + (size_t)blk * HW * C_IN;
    for (int j = threadIdx.x; j < HW * C_IN; j += 256) {
        int x = j >> 7, c = j & 127;
        dst[j] = f2h(tile[c * 57 + x]);
    }
}

// ---------------- P2: weight -> W3 lane-contiguous fragments ----------------
// W3 idx = (((t*4+ks)*16+mtg)*64+lane)*8+e ; oc = mtg*16+(lane&15), ic = ks*32+(lane>>4)*8+e
__global__ void k_weight(const float* __restrict__ w, unsigned short* __restrict__ W3) {
    int idx = blockIdx.x * 256 + threadIdx.x;
    if (idx >= C_OUT * KTOT) return;
    int e = idx & 7;
    int lane = (idx >> 3) & 63;
    int mtg = (idx >> 9) & 15;
    int ks = (idx >> 13) & 3;
    int t = idx >> 15;                 // 0..8
    int oc = mtg * 16 + (lane & 15);
    int ic = ks * 32 + (lane >> 4) * 8 + e;
    int j = t / 3, i = t % 3;
    W3[idx] = f2h(w[((oc * C_IN + ic) * 3 + j) * 3 + i]);
}

// ---------------- P3: offset [B][18][x][y] -> sxy[tc][px] unnormalized coords ----------------
__global__ void k_coords(const float* __restrict__ off, float* __restrict__ sxy) {
    __shared__ float tile[HW * 57];
    int blk = blockIdx.x;              // b*18 + tc
    int b = blk / 18, tc = blk % 18;
    const float* src = off + (size_t)blk * PLANE;
    for (int i = threadIdx.x; i < PLANE; i += 256) {
        int xx = i / HW, yy = i % HW;
        tile[xx * 57 + yy] = src[i];
    }
    __syncthreads();
    float* dst = sxy + (size_t)tc * NPX + (size_t)b * PLANE;
    bool isx = (tc & 1) == 0;
    for (int p = threadIdx.x; p < PLANE; p += 256) {
        int y = p / HW, x = p % HW;
        float v = tile[x * 57 + y];
        float a = isx ? ((float)x - 27.5f) * (1.0f / 27.5f)
                      : ((float)y - 27.5f) * (1.0f / 27.5f);
        dst[p] = (v + a + 1.0f) * 28.0f - 0.5f;
    }
}

// ---------------- P4a: coalesced sampler ----------------
// Lane = CHANNEL (64 lanes x 4B = one full 256B corner row), pixel loop q unrolled.
// Per-pixel corner offsets/weights computed vector-wide (lane = q*4+c) then broadcast
// via readlane -> scalar-base fully-coalesced loads. Depth-4 software pipeline:
// FIN(qq) retires slot qq&3, THEN ISS(qq+4) refills it (R6 bug: issue-before-finish
// clobbered the slot -> 12/16 pixels got the wrong corner data).
// V4 layout: [blk][tap][px_in_blk(64)][128ch f16]  (tap tile = 16KB contiguous).
__global__ __launch_bounds__(256, 8) void k_sample(const unsigned short* __restrict__ fws,
                                                   const float* __restrict__ sxy,
                                                   unsigned char* __restrict__ V4) {
    __shared__ float cs[18][64];
    const int tid = threadIdx.x;
    const int wave = tid >> 6, lane = tid & 63;
    const int lb = (blockIdx.x & 7) * BPER + (blockIdx.x >> 3);   // XCD-chunked swizzle
    const int gpx0 = lb * 64;
    for (int i = tid; i < 18 * 64; i += 256) {
        int tc = i >> 6, pp = i & 63;
        cs[tc][pp] = sxy[(size_t)tc * NPX + gpx0 + pp];
    }
    __syncthreads();

    const unsigned char* fimg =
        (const unsigned char*)(fws + (size_t)(gpx0 / PLANE) * (PLANE * C_IN));
    unsigned char* vblk = V4 + (size_t)lb * VBLK_STRIDE;
    const int q = lane >> 2, c = lane & 3;       // phase-A role: pixel q, corner c
    const int cx = c & 1, cy = c >> 1;
    const int pl = wave * 16 + q;                // pixel (block-local) this lane computes
    const int lane4 = lane * 4;

    uint32_t d[4][4];        // pipelined gathered dwords [slot][corner]
    f16x2 wv[4][4];          // broadcast weights (packed f16 splat)

#pragma unroll
    for (int t = 0; t < KTAPS; t++) {
        // ---- phase A: 64 lanes compute 16 px x 4 corners (offset, weight) ----
        float ixv = cs[2 * t][pl], iyv = cs[2 * t + 1][pl];
        float fx0 = floorf(ixv), fy0 = floorf(iyv);
        float wx1 = ixv - fx0, wy1 = iyv - fy0;
        int ix0 = (int)fx0, iy0 = (int)fy0;
        int xi = ix0 + cx, yi = iy0 + cy;
        float wf = (cx ? wx1 : 1.0f - wx1) * (cy ? wy1 : 1.0f - wy1);
        if ((unsigned)xi >= HW || (unsigned)yi >= HW) wf = 0.0f;
        int xc = min(max(xi, 0), HW - 1), yc = min(max(yi, 0), HW - 1);
        int offv = (yc * HW + xc) << 8;          // byte offset of corner row
        _Float16 hw_ = (_Float16)wf;
        uint16_t hu;
        __builtin_memcpy(&hu, &hw_, 2);
        int wpk = (int)((uint32_t)hu | ((uint32_t)hu << 16));   // f16x2 splat bits

        // ---- phase B: 16 pixels, coalesced 256B gathers, depth-4 pipeline ----
        auto ISS = [&](int qq, int slot) {
#pragma unroll
            for (int cc = 0; cc < 4; cc++) {
                int so_ = __builtin_amdgcn_readlane(offv, qq * 4 + cc);
                int wp_ = __builtin_amdgcn_readlane(wpk, qq * 4 + cc);
                __builtin_memcpy(&wv[slot][cc], &wp_, 4);
                d[slot][cc] = *(const uint32_t*)(fimg + so_ + lane4);
            }
        };
        auto FIN = [&](int qq, int slot) {
            f16x2 a0, a1, a2, a3;
            __builtin_memcpy(&a0, &d[slot][0], 4);
            __builtin_memcpy(&a1, &d[slot][1], 4);
            __builtin_memcpy(&a2, &d[slot][2], 4);
            __builtin_memcpy(&a3, &d[slot][3], 4);
            f16x2 v = a0 * wv[slot][0] + a1 * wv[slot][1] + a2 * wv[slot][2] + a3 * wv[slot][3];
            uint32_t u;
            __builtin_memcpy(&u, &v, 4);
            *(uint32_t*)(vblk + (size_t)t * 16384 + (wave * 16 + qq) * 256 + lane4) = u;
        };
        ISS(0, 0); ISS(1, 1); ISS(2, 2); ISS(3, 3);
#pragma unroll
        for (int qq = 0; qq < 16; qq++) {
            FIN(qq, qq & 3);                       // retire slot first...
            if (qq < 12) ISS(qq + 4, (qq + 4) & 3); // ...then refill it
        }
    }
}

// ---------------- P4b: LDS-staged dense GEMM  out[256][NPX] = W x V ----------------
// block = 64 px x 256 oc, 4 waves (wave w: oc [64w,64w+64)). Per tap (K=128):
//   top:   issue next tap's 16KB tile as coalesced 16B/thread global loads (T14 split)
//   body:  4 ks rounds { prefetch A-frags ; 4 ds_read_b128 B-frags ; 16 MFMA }
//   tail:  sched_barrier ; ds_write staged tile (XOR-swizzled) ; barrier
// LDS tile Vt[2][64px][256B], chunk swizzle c16 ^= px&7 on write AND read (16-way -> free).
__global__ __launch_bounds__(256, 3) void k_gemm(const unsigned short* __restrict__ W3,
                                                 const unsigned char* __restrict__ V4,
                                                 float* __restrict__ out) {
    __shared__ __align__(16) unsigned char Vt[2][16384];
    const int tid = threadIdx.x;
    const int wave = tid >> 6, lane = tid & 63;
    const int l16 = lane & 15, grp = lane >> 4;
    const int lb = (blockIdx.x & 7) * BPER + (blockIdx.x >> 3);   // same swizzle as sampler
    const int gpx0 = lb * 64;
    const unsigned char* vblk = V4 + (size_t)lb * VBLK_STRIDE;

    f32x4 acc[4][4];
#pragma unroll
    for (int m = 0; m < 4; m++)
#pragma unroll
        for (int n = 0; n < 4; n++) acc[m][n] = (f32x4)0.0f;

    f16x8 A[2][4];
    u32x4 sv[4];                       // staged 16B x 4 per thread

    auto SLOAD = [&](int t) {          // coalesced global reads of tap-t tile
#pragma unroll
        for (int j = 0; j < 4; j++)
            sv[j] = *(const u32x4*)(vblk + (size_t)t * 16384 + wave * 4096 + j * 1024 + lane * 16);
    };
    auto SWRITE = [&](int buf) {       // swizzled ds_write_b128
#pragma unroll
        for (int j = 0; j < 4; j++) {
            int px = wave * 16 + j * 4 + (lane >> 4);
            int c16 = lane & 15;
            *(u32x4*)(&Vt[buf][px * 256 + ((c16 ^ (px & 7)) << 4)]) = sv[j];
        }
    };
    auto loadA = [&](int slot, int t, int ks) {
        const unsigned short* wb = W3 + (size_t)((t * 4 + ks) * 16 + wave * 4) * 512 + lane * 8;
#pragma unroll
        for (int mt = 0; mt < 4; mt++)
            A[slot][mt] = *(const f16x8*)(wb + mt * 512);
    };
    auto gemm_ks = [&](int ks, int buf, int slot) {
        f16x8 bv[4];
#pragma unroll
        for (int nt = 0; nt < 4; nt++) {
            int px = nt * 16 + l16;
            int g16 = ks * 4 + grp;
            bv[nt] = *(const f16x8*)(&Vt[buf][px * 256 + ((g16 ^ (px & 7)) << 4)]);
        }
#pragma unroll
        for (int mt = 0; mt < 4; mt++)
#pragma unroll
            for (int nt = 0; nt < 4; nt++)
                acc[mt][nt] = __builtin_amdgcn_mfma_f32_16x16x32_f16(A[slot][mt], bv[nt], acc[mt][nt], 0, 0, 0);
    };

    // prologue: stage tap 0 into buf 0
    SLOAD(0);
    SWRITE(0);
    loadA(0, 0, 0);
    __syncthreads();

#pragma unroll
    for (int t = 0; t < KTAPS; t++) {
        const int buf = t & 1;
        const bool more = (t < KTAPS - 1);
        if (more) SLOAD(t + 1);                 // issue early: full tap of MFMA cover
        loadA(1, t, 1);
        gemm_ks(0, buf, 0);
        loadA(0, t, 2);
        gemm_ks(1, buf, 1);
        loadA(1, t, 3);
        gemm_ks(2, buf, 0);
        if (more) loadA(0, t + 1, 0);
        gemm_ks(3, buf, 1);
        if (more) {
            __builtin_amdgcn_sched_barrier(0);  // keep SWRITE's vmcnt wait below the MFMAs
            SWRITE(buf ^ 1);
            __syncthreads();
        }
    }

    // epilogue: col px = gpx0 + nt*16 + l16 ; row oc = wave*64 + mt*16 + grp*4 + r
    int bb = gpx0 / PLANE, rr0 = gpx0 - bb * PLANE;
    float* obase = out + (size_t)bb * C_OUT * PLANE + rr0 + l16;
#pragma unroll
    for (int nt = 0; nt < 4; nt++) {
        float* ob = obase + nt * 16;
#pragma unroll
        for (int mt = 0; mt < 4; mt++) {
#pragma unroll
            for (int r = 0; r < 4; r++) {
                int oc = wave * 64 + mt * 16 + grp * 4 + r;
                ob[(size_t)oc * PLANE] = acc[mt][nt][r];
            }
        }
    }
}

// ---------------- fallback: fused sampler+GEMM (R3 structure), ws-light ----------------
__global__ __launch_bounds__(256, 2) void k_fused(const unsigned short* __restrict__ fws,
                                                  const unsigned short* __restrict__ W3,
                                                  const float* __restrict__ sxy,
                                                  float* __restrict__ out) {
    __shared__ float cs[18][64];
    const int tid = threadIdx.x;
    const int wave = tid >> 6, lane = tid & 63;
    const int l16 = lane & 15, grp = lane >> 4;
    const int lbid = (blockIdx.x & 7) * (NBLK64 / 8) + (blockIdx.x >> 3);
    const int px0 = lbid * 64;
    const unsigned short* fb = fws + (size_t)(px0 / PLANE) * (PLANE * C_IN) + grp * 8;
    for (int i = tid; i < 18 * 64; i += 256) {
        int tc = i >> 6, pp = i & 63;
        cs[tc][pp] = sxy[(size_t)tc * NPX + px0 + pp];
    }
    __syncthreads();
    const int p = wave * 16 + l16;
    f32x4 acc[16];
#pragma unroll
    for (int m = 0; m < 16; m++) acc[m] = (f32x4)0.0f;
    f16x8 cv[4][4];
    float swc[4], swn[4];
    const unsigned short *c00, *c10, *c01, *c11;
    auto calc_tap = [&](int t, float* sw) {
        float ixv = cs[2 * t][p], iyv = cs[2 * t + 1][p];
        float fx0 = floorf(ixv), fy0 = floorf(iyv);
        float wx1 = ixv - fx0, wy1 = iyv - fy0;
        float wx0 = 1.0f - wx1, wy0 = 1.0f - wy1;
        int ix0 = (int)fx0, iy0 = (int)fy0, ix1 = ix0 + 1, iy1 = iy0 + 1;
        float vx0 = ((unsigned)ix0 < HW) ? 1.0f : 0.0f;
        float vx1 = ((unsigned)ix1 < HW) ? 1.0f : 0.0f;
        float vy0 = ((unsigned)iy0 < HW) ? 1.0f : 0.0f;
        float vy1 = ((unsigned)iy1 < HW) ? 1.0f : 0.0f;
        int xc0 = min(max(ix0, 0), HW - 1), xc1 = min(max(ix1, 0), HW - 1);
        int yc0 = min(max(iy0, 0), HW - 1), yc1 = min(max(iy1, 0), HW - 1);
        const unsigned short* r0 = fb + (size_t)(yc0 * HW) * C_IN;
        const unsigned short* r1 = fb + (size_t)(yc1 * HW) * C_IN;
        c00 = r0 + xc0 * C_IN; c10 = r0 + xc1 * C_IN;
        c01 = r1 + xc0 * C_IN; c11 = r1 + xc1 * C_IN;
        sw[0] = wx0 * wy0 * vx0 * vy0; sw[1] = wx1 * wy0 * vx1 * vy0;
        sw[2] = wx0 * wy1 * vx0 * vy1; sw[3] = wx1 * wy1 * vx1 * vy1;
    };
    auto sample_ks = [&](int ks) {
        cv[0][ks] = *(const f16x8*)(c00 + ks * 32);
        cv[1][ks] = *(const f16x8*)(c10 + ks * 32);
        cv[2][ks] = *(const f16x8*)(c01 + ks * 32);
        cv[3][ks] = *(const f16x8*)(c11 + ks * 32);
    };
    calc_tap(0, swc);
#pragma unroll
    for (int ks = 0; ks < 4; ks++) sample_ks(ks);
#pragma unroll
    for (int t = 0; t < KTAPS; t++) {
        const bool more = (t < KTAPS - 1);
        if (more) calc_tap(t + 1, swn);
#pragma unroll
        for (int ks = 0; ks < 4; ks++) {
            f16x8 v = cv[0][ks] * (f16x8)(_Float16)swc[0]
                    + cv[1][ks] * (f16x8)(_Float16)swc[1]
                    + cv[2][ks] * (f16x8)(_Float16)swc[2]
                    + cv[3][ks] * (f16x8)(_Float16)swc[3];
            const unsigned short* wb = W3 + (size_t)(t * 4 + ks) * 8192 + lane * 8;
            f16x8 af[16];
#pragma unroll
            for (int mtg = 0; mtg < 16; mtg++)
                af[mtg] = *(const f16x8*)(wb + mtg * 512);
            if (more) sample_ks(ks);
#pragma unroll
            for (int mtg = 0; mtg < 16; mtg++)
                acc[mtg] = __builtin_amdgcn_mfma_f32_16x16x32_f16(af[mtg], v, acc[mtg], 0, 0, 0);
        }
        if (more) {
#pragma unroll
            for (int c = 0; c < 4; c++) swc[c] = swn[c];
        }
    }
    int bb = px0 / PLANE, rr = px0 - bb * PLANE + p;
    float* ob = out + (size_t)bb * C_OUT * PLANE + rr;
#pragma unroll
    for (int mtg = 0; mtg < 16; mtg++)
#pragma unroll
        for (int r = 0; r < 4; r++)
            ob[(size_t)(mtg * 16 + grp * 4 + r) * PLANE] = acc[mtg][r];
}

extern "C" void kernel_launch(void* const* d_in, const int* in_sizes, int n_in,
                              void* d_out, int out_size, void* d_ws, size_t ws_size,
                              hipStream_t stream) {
    const float* feature = (const float*)d_in[0];
    const float* offset = (const float*)d_in[1];
    const float* weight = (const float*)d_in[2];
    float* out = (float*)d_out;

    char* ws = (char*)d_ws;
    unsigned short* fws = (unsigned short*)ws;                          // 25,690,112 B
    unsigned short* W3 = (unsigned short*)(ws + 25690112);              // 589,824 B
    float* sxy = (float*)(ws + 25690112 + 589824);                      // 7,225,344 B
    const size_t base = 25690112 + 589824 + 7225344;                    // 33,505,280 B
    const size_t v4_full = (size_t)NBLK64 * VBLK_STRIDE;                // 231,211,008 B
    unsigned char* V4 = (unsigned char*)(ws + base);

    k_feat_nhwc<<<BATCH * HW, 256, 0, stream>>>(feature, fws);
    k_weight<<<(C_OUT * KTOT + 255) / 256, 256, 0, stream>>>(weight, W3);
    k_coords<<<BATCH * 18, 256, 0, stream>>>(offset, sxy);

    if (ws_size >= base + v4_full) {
        k_sample<<<NBLK64, 256, 0, stream>>>(fws, sxy, V4);
        k_gemm<<<NBLK64, 256, 0, stream>>>(W3, V4, out);
    } else {
        k_fused<<<NBLK64, 256, 0, stream>>>(fws, W3, sxy, out);
    }
}

// Round 8
// 203.163 us; speedup vs baseline: 1.6836x; 1.1159x over previous
//
#include <hip/hip_runtime.h>
#include <hip/hip_bf16.h>
#include <stdint.h>

#define KTAPS 9
#define C_IN 128
#define C_OUT 256
#define HW 56
#define PLANE 3136           // 56*56
#define BATCH 32
#define NPX (BATCH * PLANE)  // 100352
#define KTOT 1152            // 9*128
#define NBLK64 (NPX / 64)    // 1568 blocks (64 px each)
#define CHBLK (NBLK64 / 2)   // 784 blocks per chunk
#define CHPER (CHBLK / 8)    // 98 per XCD
#define VBLK_STRIDE (KTAPS * 16384)   // 147456 B per 64-px block in V4

typedef __attribute__((ext_vector_type(8))) _Float16 f16x8;
typedef __attribute__((ext_vector_type(2))) _Float16 f16x2;
typedef __attribute__((ext_vector_type(4))) float f32x4;
typedef __attribute__((ext_vector_type(4))) unsigned int u32x4;

static __device__ __forceinline__ uint16_t f2h(float f) {
    _Float16 h = (_Float16)f;
    uint16_t u;
    __builtin_memcpy(&u, &h, 2);
    return u;
}

// ---------------- P1: feature NCHW fp32 -> NHWC f16 ----------------
__global__ void k_feat_nhwc(const float* __restrict__ f, unsigned short* __restrict__ fws) {
    __shared__ float tile[C_IN * 57];
    int blk = blockIdx.x;              // b*56 + y
    int b = blk / HW, y = blk % HW;
    const float* src = f + (size_t)b * C_IN * PLANE + y * HW;
    for (int i = threadIdx.x; i < C_IN * HW; i += 256) {
        int c = i / HW, x = i % HW;
        tile[c * 57 + x] = src[(size_t)c * PLANE + x];
    }
    __syncthreads();
    unsigned short* dst = fws + (size_t)blk * HW * C_IN;
    for (int j = threadIdx.x; j < HW * C_IN; j += 256) {
        int x = j >> 7, c = j & 127;
        dst[j] = f2h(tile[c * 57 + x]);
    }
}

// ---------------- P2: weight -> W3 lane-contiguous fragments ----------------
// W3 idx = (((t*4+ks)*16+mtg)*64+lane)*8+e ; oc = mtg*16+(lane&15), ic = ks*32+(lane>>4)*8+e
__global__ void k_weight(const float* __restrict__ w, unsigned short* __restrict__ W3) {
    int idx = blockIdx.x * 256 + threadIdx.x;
    if (idx >= C_OUT * KTOT) return;
    int e = idx & 7;
    int lane = (idx >> 3) & 63;
    int mtg = (idx >> 9) & 15;
    int ks = (idx >> 13) & 3;
    int t = idx >> 15;                 // 0..8
    int oc = mtg * 16 + (lane & 15);
    int ic = ks * 32 + (lane >> 4) * 8 + e;
    int j = t / 3, i = t % 3;
    W3[idx] = f2h(w[((oc * C_IN + ic) * 3 + j) * 3 + i]);
}

// ---------------- P3: offset [B][18][x][y] -> sxy[tc][px] unnormalized coords ----------------
__global__ void k_coords(const float* __restrict__ off, float* __restrict__ sxy) {
    __shared__ float tile[HW * 57];
    int blk = blockIdx.x;              // b*18 + tc
    int b = blk / 18, tc = blk % 18;
    const float* src = off + (size_t)blk * PLANE;
    for (int i = threadIdx.x; i < PLANE; i += 256) {
        int xx = i / HW, yy = i % HW;
        tile[xx * 57 + yy] = src[i];
    }
    __syncthreads();
    float* dst = sxy + (size_t)tc * NPX + (size_t)b * PLANE;
    bool isx = (tc & 1) == 0;
    for (int p = threadIdx.x; p < PLANE; p += 256) {
        int y = p / HW, x = p % HW;
        float v = tile[x * 57 + y];
        float a = isx ? ((float)x - 27.5f) * (1.0f / 27.5f)
                      : ((float)y - 27.5f) * (1.0f / 27.5f);
        dst[p] = (v + a + 1.0f) * 28.0f - 0.5f;
    }
}

// ---------------- P4a: coalesced sampler (chunked) ----------------
// Lane = CHANNEL (64 lanes x 4B = one full 256B corner row). Depth-4 FIN-then-ISS
// pipeline (R7-verified). V4 indexed CHUNK-LOCALLY: chunk = 784 blocks = 115.6MB,
// fits L3 -> gemm reads hit L3.
__global__ __launch_bounds__(256, 8) void k_sample(const unsigned short* __restrict__ fws,
                                                   const float* __restrict__ sxy,
                                                   unsigned char* __restrict__ V4,
                                                   int lb0) {
    __shared__ float cs[18][64];
    const int tid = threadIdx.x;
    const int wave = tid >> 6, lane = tid & 63;
    const int lb = (blockIdx.x & 7) * CHPER + (blockIdx.x >> 3);   // XCD-chunked swizzle
    const int gpx0 = (lb0 + lb) * 64;
    for (int i = tid; i < 18 * 64; i += 256) {
        int tc = i >> 6, pp = i & 63;
        cs[tc][pp] = sxy[(size_t)tc * NPX + gpx0 + pp];
    }
    __syncthreads();

    const unsigned char* fimg =
        (const unsigned char*)(fws + (size_t)(gpx0 / PLANE) * (PLANE * C_IN));
    unsigned char* vblk = V4 + (size_t)lb * VBLK_STRIDE;           // chunk-local
    const int q = lane >> 2, c = lane & 3;
    const int cx = c & 1, cy = c >> 1;
    const int pl = wave * 16 + q;
    const int lane4 = lane * 4;

    uint32_t d[4][4];
    f16x2 wv[4][4];

#pragma unroll
    for (int t = 0; t < KTAPS; t++) {
        float ixv = cs[2 * t][pl], iyv = cs[2 * t + 1][pl];
        float fx0 = floorf(ixv), fy0 = floorf(iyv);
        float wx1 = ixv - fx0, wy1 = iyv - fy0;
        int ix0 = (int)fx0, iy0 = (int)fy0;
        int xi = ix0 + cx, yi = iy0 + cy;
        float wf = (cx ? wx1 : 1.0f - wx1) * (cy ? wy1 : 1.0f - wy1);
        if ((unsigned)xi >= HW || (unsigned)yi >= HW) wf = 0.0f;
        int xc = min(max(xi, 0), HW - 1), yc = min(max(yi, 0), HW - 1);
        int offv = (yc * HW + xc) << 8;
        _Float16 hw_ = (_Float16)wf;
        uint16_t hu;
        __builtin_memcpy(&hu, &hw_, 2);
        int wpk = (int)((uint32_t)hu | ((uint32_t)hu << 16));

        auto ISS = [&](int qq, int slot) {
#pragma unroll
            for (int cc = 0; cc < 4; cc++) {
                int so_ = __builtin_amdgcn_readlane(offv, qq * 4 + cc);
                int wp_ = __builtin_amdgcn_readlane(wpk, qq * 4 + cc);
                __builtin_memcpy(&wv[slot][cc], &wp_, 4);
                d[slot][cc] = *(const uint32_t*)(fimg + so_ + lane4);
            }
        };
        auto FIN = [&](int qq, int slot) {
            f16x2 a0, a1, a2, a3;
            __builtin_memcpy(&a0, &d[slot][0], 4);
            __builtin_memcpy(&a1, &d[slot][1], 4);
            __builtin_memcpy(&a2, &d[slot][2], 4);
            __builtin_memcpy(&a3, &d[slot][3], 4);
            f16x2 v = a0 * wv[slot][0] + a1 * wv[slot][1] + a2 * wv[slot][2] + a3 * wv[slot][3];
            uint32_t u;
            __builtin_memcpy(&u, &v, 4);
            *(uint32_t*)(vblk + (size_t)t * 16384 + (wave * 16 + qq) * 256 + lane4) = u;
        };
        ISS(0, 0); ISS(1, 1); ISS(2, 2); ISS(3, 3);
#pragma unroll
        for (int qq = 0; qq < 16; qq++) {
            FIN(qq, qq & 3);                        // retire slot first...
            if (qq < 12) ISS(qq + 4, (qq + 4) & 3); // ...then refill it
        }
    }
}

// ---------------- P4b: LDS-staged dense GEMM (vmcnt-order-correct pipeline) ----------------
// Per tap t:  1) SWRITE sv[(t+1)&1] -> buf[(t+1)&1]   (waits on SLOAD issued a FULL tap ago ~ 0 stall)
//             2) loadA ALL 4 ks slots (16 L2 loads)   (older than SLOAD -> gemm waits never drain it)
//             3) SLOAD(t+2) -> sv[t&1]                (YOUNGEST load in the queue, by construction)
//             4) 4x gemm_ks from buf[t&1]             (counted vmcnt on A only)
//             5) barrier
// In-order vmcnt discipline: the slow V4 stream is always the youngest issue, so no
// compute wait ever drains it (R7 bug: SLOAD issued before loadA -> forced drain per tap).
__global__ __launch_bounds__(256, 2) void k_gemm(const unsigned short* __restrict__ W3,
                                                 const unsigned char* __restrict__ V4,
                                                 float* __restrict__ out,
                                                 int lb0) {
    __shared__ __align__(16) unsigned char Vt[2][16384];
    const int tid = threadIdx.x;
    const int wave = tid >> 6, lane = tid & 63;
    const int l16 = lane & 15, grp = lane >> 4;
    const int lb = (blockIdx.x & 7) * CHPER + (blockIdx.x >> 3);   // same mapping as sampler
    const int gpx0 = (lb0 + lb) * 64;
    const unsigned char* vblk = V4 + (size_t)lb * VBLK_STRIDE;     // chunk-local

    f32x4 acc[4][4];
#pragma unroll
    for (int m = 0; m < 4; m++)
#pragma unroll
        for (int n = 0; n < 4; n++) acc[m][n] = (f32x4)0.0f;

    f16x8 A[4][4];                     // full tap of weight fragments (64 VGPR)
    u32x4 sv[2][4];                    // 2-tap lookahead staging regs

    auto SLOAD = [&](int set, int t) {
#pragma unroll
        for (int j = 0; j < 4; j++)
            sv[set][j] = *(const u32x4*)(vblk + (size_t)t * 16384 + wave * 4096 + j * 1024 + lane * 16);
    };
    auto SWRITE = [&](int set, int buf) {
#pragma unroll
        for (int j = 0; j < 4; j++) {
            int px = wave * 16 + j * 4 + (lane >> 4);
            int c16 = lane & 15;
            *(u32x4*)(&Vt[buf][px * 256 + ((c16 ^ (px & 7)) << 4)]) = sv[set][j];
        }
    };
    auto loadA = [&](int ks, int t) {
        const unsigned short* wb = W3 + (size_t)((t * 4 + ks) * 16 + wave * 4) * 512 + lane * 8;
#pragma unroll
        for (int mt = 0; mt < 4; mt++)
            A[ks][mt] = *(const f16x8*)(wb + mt * 512);
    };
    auto gemm_ks = [&](int ks, int buf) {
        f16x8 bv[4];
#pragma unroll
        for (int nt = 0; nt < 4; nt++) {
            int px = nt * 16 + l16;
            int g16 = ks * 4 + grp;
            bv[nt] = *(const f16x8*)(&Vt[buf][px * 256 + ((g16 ^ (px & 7)) << 4)]);
        }
#pragma unroll
        for (int mt = 0; mt < 4; mt++)
#pragma unroll
            for (int nt = 0; nt < 4; nt++)
                acc[mt][nt] = __builtin_amdgcn_mfma_f32_16x16x32_f16(A[ks][mt], bv[nt], acc[mt][nt], 0, 0, 0);
    };

    // prologue: buf0 <- tap0 ; sv[1] <- tap1 (in flight)
    SLOAD(0, 0);
    SWRITE(0, 0);                      // cold vmcnt wait, once
    SLOAD(1, 1);
    __syncthreads();

#pragma unroll
    for (int t = 0; t < KTAPS; t++) {
        const int buf = t & 1;
        if (t < KTAPS - 1) SWRITE((t + 1) & 1, (t + 1) & 1);  // data SLOADed one full tap ago
        loadA(0, t); loadA(1, t); loadA(2, t); loadA(3, t);   // L2-hot, issued BEFORE SLOAD
        __builtin_amdgcn_sched_barrier(0);                    // pin: A-loads above, SLOAD below
        if (t < KTAPS - 2) SLOAD(t & 1, t + 2);               // youngest -> never force-drained
        __builtin_amdgcn_sched_barrier(0);
        gemm_ks(0, buf); gemm_ks(1, buf); gemm_ks(2, buf); gemm_ks(3, buf);
        if (t < KTAPS - 1) __syncthreads();
    }

    // epilogue: col px = gpx0 + nt*16 + l16 ; row oc = wave*64 + mt*16 + grp*4 + r
    int bb = gpx0 / PLANE, rr0 = gpx0 - bb * PLANE;
    float* obase = out + (size_t)bb * C_OUT * PLANE + rr0 + l16;
#pragma unroll
    for (int nt = 0; nt < 4; nt++) {
        float* ob = obase + nt * 16;
#pragma unroll
        for (int mt = 0; mt < 4; mt++) {
#pragma unroll
            for (int r = 0; r < 4; r++) {
                int oc = wave * 64 + mt * 16 + grp * 4 + r;
                ob[(size_t)oc * PLANE] = acc[mt][nt][r];
            }
        }
    }
}

// ---------------- fallback: fused sampler+GEMM (R3 structure), ws-light ----------------
__global__ __launch_bounds__(256, 2) void k_fused(const unsigned short* __restrict__ fws,
                                                  const unsigned short* __restrict__ W3,
                                                  const float* __restrict__ sxy,
                                                  float* __restrict__ out) {
    __shared__ float cs[18][64];
    const int tid = threadIdx.x;
    const int wave = tid >> 6, lane = tid & 63;
    const int l16 = lane & 15, grp = lane >> 4;
    const int lbid = (blockIdx.x & 7) * (NBLK64 / 8) + (blockIdx.x >> 3);
    const int px0 = lbid * 64;
    const unsigned short* fb = fws + (size_t)(px0 / PLANE) * (PLANE * C_IN) + grp * 8;
    for (int i = tid; i < 18 * 64; i += 256) {
        int tc = i >> 6, pp = i & 63;
        cs[tc][pp] = sxy[(size_t)tc * NPX + px0 + pp];
    }
    __syncthreads();
    const int p = wave * 16 + l16;
    f32x4 acc[16];
#pragma unroll
    for (int m = 0; m < 16; m++) acc[m] = (f32x4)0.0f;
    f16x8 cv[4][4];
    float swc[4], swn[4];
    const unsigned short *c00, *c10, *c01, *c11;
    auto calc_tap = [&](int t, float* sw) {
        float ixv = cs[2 * t][p], iyv = cs[2 * t + 1][p];
        float fx0 = floorf(ixv), fy0 = floorf(iyv);
        float wx1 = ixv - fx0, wy1 = iyv - fy0;
        float wx0 = 1.0f - wx1, wy0 = 1.0f - wy1;
        int ix0 = (int)fx0, iy0 = (int)fy0, ix1 = ix0 + 1, iy1 = iy0 + 1;
        float vx0 = ((unsigned)ix0 < HW) ? 1.0f : 0.0f;
        float vx1 = ((unsigned)ix1 < HW) ? 1.0f : 0.0f;
        float vy0 = ((unsigned)iy0 < HW) ? 1.0f : 0.0f;
        float vy1 = ((unsigned)iy1 < HW) ? 1.0f : 0.0f;
        int xc0 = min(max(ix0, 0), HW - 1), xc1 = min(max(ix1, 0), HW - 1);
        int yc0 = min(max(iy0, 0), HW - 1), yc1 = min(max(iy1, 0), HW - 1);
        const unsigned short* r0 = fb + (size_t)(yc0 * HW) * C_IN;
        const unsigned short* r1 = fb + (size_t)(yc1 * HW) * C_IN;
        c00 = r0 + xc0 * C_IN; c10 = r0 + xc1 * C_IN;
        c01 = r1 + xc0 * C_IN; c11 = r1 + xc1 * C_IN;
        sw[0] = wx0 * wy0 * vx0 * vy0; sw[1] = wx1 * wy0 * vx1 * vy0;
        sw[2] = wx0 * wy1 * vx0 * vy1; sw[3] = wx1 * wy1 * vx1 * vy1;
    };
    auto sample_ks = [&](int ks) {
        cv[0][ks] = *(const f16x8*)(c00 + ks * 32);
        cv[1][ks] = *(const f16x8*)(c10 + ks * 32);
        cv[2][ks] = *(const f16x8*)(c01 + ks * 32);
        cv[3][ks] = *(const f16x8*)(c11 + ks * 32);
    };
    calc_tap(0, swc);
#pragma unroll
    for (int ks = 0; ks < 4; ks++) sample_ks(ks);
#pragma unroll
    for (int t = 0; t < KTAPS; t++) {
        const bool more = (t < KTAPS - 1);
        if (more) calc_tap(t + 1, swn);
#pragma unroll
        for (int ks = 0; ks < 4; ks++) {
            f16x8 v = cv[0][ks] * (f16x8)(_Float16)swc[0]
                    + cv[1][ks] * (f16x8)(_Float16)swc[1]
                    + cv[2][ks] * (f16x8)(_Float16)swc[2]
                    + cv[3][ks] * (f16x8)(_Float16)swc[3];
            const unsigned short* wb = W3 + (size_t)(t * 4 + ks) * 8192 + lane * 8;
            f16x8 af[16];
#pragma unroll
            for (int mtg = 0; mtg < 16; mtg++)
                af[mtg] = *(const f16x8*)(wb + mtg * 512);
            if (more) sample_ks(ks);
#pragma unroll
            for (int mtg = 0; mtg < 16; mtg++)
                acc[mtg] = __builtin_amdgcn_mfma_f32_16x16x32_f16(af[mtg], v, acc[mtg], 0, 0, 0);
        }
        if (more) {
#pragma unroll
            for (int c = 0; c < 4; c++) swc[c] = swn[c];
        }
    }
    int bb = px0 / PLANE, rr = px0 - bb * PLANE + p;
    float* ob = out + (size_t)bb * C_OUT * PLANE + rr;
#pragma unroll
    for (int mtg = 0; mtg < 16; mtg++)
#pragma unroll
        for (int r = 0; r < 4; r++)
            ob[(size_t)(mtg * 16 + grp * 4 + r) * PLANE] = acc[mtg][r];
}

extern "C" void kernel_launch(void* const* d_in, const int* in_sizes, int n_in,
                              void* d_out, int out_size, void* d_ws, size_t ws_size,
                              hipStream_t stream) {
    const float* feature = (const float*)d_in[0];
    const float* offset = (const float*)d_in[1];
    const float* weight = (const float*)d_in[2];
    float* out = (float*)d_out;

    char* ws = (char*)d_ws;
    unsigned short* fws = (unsigned short*)ws;                          // 25,690,112 B
    unsigned short* W3 = (unsigned short*)(ws + 25690112);              // 589,824 B
    float* sxy = (float*)(ws + 25690112 + 589824);                      // 7,225,344 B
    const size_t base = 25690112 + 589824 + 7225344;                    // 33,505,280 B
    const size_t v4_half = (size_t)CHBLK * VBLK_STRIDE;                 // 115,605,504 B
    unsigned char* V4 = (unsigned char*)(ws + base);

    k_feat_nhwc<<<BATCH * HW, 256, 0, stream>>>(feature, fws);
    k_weight<<<(C_OUT * KTOT + 255) / 256, 256, 0, stream>>>(weight, W3);
    k_coords<<<BATCH * 18, 256, 0, stream>>>(offset, sxy);

    if (ws_size >= base + v4_half) {
        // 2 chunks, single half-buffer (stream-serial keeps it correct; chunk fits L3)
        for (int c = 0; c < 2; c++) {
            k_sample<<<CHBLK, 256, 0, stream>>>(fws, sxy, V4, c * CHBLK);
            k_gemm<<<CHBLK, 256, 0, stream>>>(W3, V4, out, c * CHBLK);
        }
    } else {
        k_fused<<<NBLK64, 256, 0, stream>>>(fws, W3, sxy, out);
    }
}